// Round 5
// baseline (1025.327 us; speedup 1.0000x reference)
//
#include <hip/hip_runtime.h>
#include <math.h>

typedef unsigned short u16;
typedef u16 u16x8 __attribute__((ext_vector_type(8)));
typedef __bf16 bf16x8 __attribute__((ext_vector_type(8)));
typedef float f32x4 __attribute__((ext_vector_type(4)));
typedef float f32x2 __attribute__((ext_vector_type(2)));

#define HID 200
#define G4H 800
#define TLEN 128
#define LATENT 128
#define NCODES 1024
#define DIN 768
#define DCOND 1536
#define NB 256
#define MROWS (NB * TLEN)
#define LDG 896
#define LDH1 256
#define LDH2 512
#define NOUT 768

__device__ __forceinline__ u16 f2b(float f) {
  union { float f; unsigned u; } v; v.f = f;
  unsigned r = v.u + 0x7fffu + ((v.u >> 16) & 1u);
  return (u16)(r >> 16);
}
__device__ __forceinline__ float b2f(u16 h) {
  union { unsigned u; float f; } v; v.u = ((unsigned)h) << 16;
  return v.f;
}
__device__ __forceinline__ float sigf(float x) { return 1.f / (1.f + __expf(-x)); }
__device__ __forceinline__ float tanh_fast(float x) {
  return 1.f - 2.f / (__expf(2.f * x) + 1.f);
}

// manual fp8 e4m3fn encode (OCP; matches gfx950 v_cvt_pk_f32_fp8 decode)
__device__ __forceinline__ unsigned enc_e4m3(float v) {
  union { float f; unsigned u; } x; x.f = v;
  unsigned s = (x.u >> 31) << 7;
  float a = fabsf(v);
  if (a == 0.f) return s;
  if (a >= 448.f) return s | 0x7E;
  int exp = (int)((x.u >> 23) & 0xFF) - 127;
  unsigned man = (x.u >> 20) & 0x7;
  unsigned rnd = (x.u >> 19) & 1;
  man += rnd;
  if (man > 7) { man = 0; exp += 1; }
  int be = exp + 7;
  if (be >= 16) return s | 0x7E;
  if (be <= 0) {  // subnormal: units of 2^-9
    int q = (int)(a * 512.f + 0.5f);
    if (q > 7) q = 7;
    return s | (unsigned)q;
  }
  return s | ((unsigned)be << 4) | man;
}

// async global->LDS, 16B per lane; LDS dest is wave-uniform base + lane*16
__device__ __forceinline__ void gl16(const void* g, void* l) {
  __builtin_amdgcn_global_load_lds(
      (const __attribute__((address_space(1))) void*)g,
      (__attribute__((address_space(3))) void*)l, 16, 0, 0);
}

// pack 2 f32 -> u32 of 2 bf16 (lo = first arg)
__device__ __forceinline__ unsigned cvtpk(float a, float b) {
  unsigned r;
  asm("v_cvt_pk_bf16_f32 %0, %1, %2" : "=v"(r) : "v"(a), "v"(b));
  return r;
}

// ---------------- weight convert + pad ----------------
__global__ void cvt_pad(const float* __restrict__ src, u16* __restrict__ dst,
                        int nr, int nc, int lds, int col0, int NRp, int KP) {
  int i = blockIdx.x * blockDim.x + threadIdx.x;
  if (i >= NRp * KP) return;
  int r = i / KP, c = i - r * KP;
  float v = (r < nr && c < nc) ? src[(size_t)r * lds + col0 + c] : 0.f;
  dst[i] = f2b(v);
}

__global__ void pad_f32(const float* __restrict__ src, float* __restrict__ dst,
                        int n, int npad) {
  int i = blockIdx.x * blockDim.x + threadIdx.x;
  if (i < npad) dst[i] = (i < n) ? src[i] : 0.f;
}

// W_hh [800][200] f32 -> Wq[j*400+r] = fp8x4( 16*W[r][2j], 16*W[r+400][2j],
//                                             16*W[r][2j+1], 16*W[r+400][2j+1] )
__global__ void pack_whh_fp8(const float* __restrict__ Whh, unsigned* __restrict__ Wq,
                             const float* __restrict__ b_ih, const float* __restrict__ b_hh,
                             float* __restrict__ biasc) {
  int i = blockIdx.x * blockDim.x + threadIdx.x;
  if (i < 100 * 400) {
    int j = i / 400, r = i - j * 400;
    int k = 2 * j;
    unsigned b0 = enc_e4m3(16.f * Whh[(size_t)r * HID + k]);
    unsigned b1 = enc_e4m3(16.f * Whh[(size_t)(r + 400) * HID + k]);
    unsigned b2 = enc_e4m3(16.f * Whh[(size_t)r * HID + k + 1]);
    unsigned b3 = enc_e4m3(16.f * Whh[(size_t)(r + 400) * HID + k + 1]);
    Wq[i] = b0 | (b1 << 8) | (b2 << 16) | (b3 << 24);
  }
  if (i < G4H) biasc[i] = b_ih[i] + b_hh[i];
}

// ---------------- bf16 MFMA GEMM: C[M,N] = A[M,K] * B[N,K]^T (+epilogue) ----------------
enum { EPI_GATES = 0, EPI_H1 = 1, EPI_H2 = 2, EPI_OUT = 3 };

__device__ __forceinline__ f32x4 mfma16(bf16x8 a, bf16x8 b, f32x4 c) {
  return __builtin_amdgcn_mfma_f32_16x16x32_bf16(a, b, c, 0, 0, 0);
}

template<bool AF32, int EPI>
__global__ __launch_bounds__(256) void gemm_bf16(
    const void* __restrict__ Ap, const u16* __restrict__ Bp,
    void* __restrict__ Cp, int K, int ldc, const float* __restrict__ bias) {
  __shared__ __attribute__((aligned(16))) char AsRaw[AF32 ? 128 * 32 * 4 : 128 * 32 * 2];
  __shared__ __attribute__((aligned(16))) u16 Bs[128 * 32];
  float* Asf = (float*)AsRaw;
  u16* As16 = (u16*)AsRaw;

  const int t = threadIdx.x;
  const int tileN = blockIdx.x * 128;
  const int tileM = blockIdx.y * 128;
  const int l = t & 63;
  const int w = t >> 6;
  const int wr = (w >> 1) * 64;
  const int wc = (w & 1) * 64;
  const int fr = l & 15;
  const int fg = l >> 4;

  const u16* bsrc[2];
  u16* bdst[2];
#pragma unroll
  for (int j = 0; j < 2; ++j) {
    int tb = w * 1024 + j * 4096 + (t & 63) * 16;
    int row = tb >> 6, gd = (tb >> 4) & 3;
    bsrc[j] = Bp + (size_t)(tileN + row) * K + ((gd ^ ((row >> 1) & 3)) << 3);
    bdst[j] = Bs + w * 512 + j * 2048;
  }
  const float* asrcF[4];
  float* adstF[4];
  const u16* asrcH[2];
  u16* adstH[2];
  if constexpr (AF32) {
#pragma unroll
    for (int j = 0; j < 4; ++j) {
      int tb = w * 1024 + j * 4096 + (t & 63) * 16;
      int row = tb >> 7, gd = (tb >> 4) & 7;
      asrcF[j] = (const float*)Ap + (size_t)(tileM + row) * K + ((gd ^ (row & 7)) << 2);
      adstF[j] = Asf + w * 256 + j * 1024;
    }
  } else {
#pragma unroll
    for (int j = 0; j < 2; ++j) {
      int tb = w * 1024 + j * 4096 + (t & 63) * 16;
      int row = tb >> 6, gd = (tb >> 4) & 3;
      asrcH[j] = (const u16*)Ap + (size_t)(tileM + row) * K + ((gd ^ ((row >> 1) & 3)) << 3);
      adstH[j] = As16 + w * 512 + j * 2048;
    }
  }

  f32x4 acc[4][4];
#pragma unroll
  for (int m = 0; m < 4; ++m)
#pragma unroll
    for (int n = 0; n < 4; ++n) {
      f32x4 z = {0.f, 0.f, 0.f, 0.f};
      acc[m][n] = z;
    }

  for (int k0 = 0; k0 < K; k0 += 32) {
#pragma unroll
    for (int j = 0; j < 2; ++j) { gl16(bsrc[j], bdst[j]); bsrc[j] += 32; }
    if constexpr (AF32) {
#pragma unroll
      for (int j = 0; j < 4; ++j) { gl16(asrcF[j], adstF[j]); asrcF[j] += 32; }
    } else {
#pragma unroll
      for (int j = 0; j < 2; ++j) { gl16(asrcH[j], adstH[j]); asrcH[j] += 32; }
    }
    __syncthreads();

    bf16x8 av[4], bv[4];
#pragma unroll
    for (int m = 0; m < 4; ++m) {
      const int row = wr + m * 16 + fr;
      if constexpr (AF32) {
        const int g0 = (2 * fg) ^ (row & 7);
        const int g1 = (2 * fg + 1) ^ (row & 7);
        float4 p0 = *(const float4*)(Asf + row * 32 + g0 * 4);
        float4 p1 = *(const float4*)(Asf + row * 32 + g1 * 4);
        uint4 u;
        u.x = cvtpk(p0.x, p0.y); u.y = cvtpk(p0.z, p0.w);
        u.z = cvtpk(p1.x, p1.y); u.w = cvtpk(p1.z, p1.w);
        av[m] = __builtin_bit_cast(bf16x8, u);
      } else {
        const int g = fg ^ ((row >> 1) & 3);
        av[m] = __builtin_bit_cast(bf16x8, *(const u16x8*)(As16 + row * 32 + g * 8));
      }
    }
#pragma unroll
    for (int n = 0; n < 4; ++n) {
      const int row = wc + n * 16 + fr;
      const int g = fg ^ ((row >> 1) & 3);
      bv[n] = __builtin_bit_cast(bf16x8, *(const u16x8*)(Bs + row * 32 + g * 8));
    }
#pragma unroll
    for (int m = 0; m < 4; ++m)
#pragma unroll
      for (int n = 0; n < 4; ++n)
        acc[m][n] = mfma16(av[m], bv[n], acc[m][n]);
    __syncthreads();
  }

#pragma unroll
  for (int m = 0; m < 4; ++m) {
#pragma unroll
    for (int n = 0; n < 4; ++n) {
      const int gcol = tileN + wc + n * 16 + fr;
      const int growb = tileM + wr + m * 16 + fg * 4;
#pragma unroll
      for (int r = 0; r < 4; ++r) {
        const int grow = growb + r;
        float v = acc[m][n][r];
        if constexpr (EPI == EPI_GATES) {
          ((u16*)Cp)[(size_t)grow * ldc + gcol] = f2b(v);
        } else if constexpr (EPI == EPI_H1) {
          v += bias[(grow >> 7) * 256 + gcol];
          v = fmaxf(v, 0.f);
          ((u16*)Cp)[(size_t)grow * ldc + gcol] = f2b(v);
        } else if constexpr (EPI == EPI_H2) {
          v += bias[gcol];
          v = fmaxf(v, 0.f);
          ((u16*)Cp)[(size_t)grow * ldc + gcol] = f2b(v);
        } else {
          v += bias[gcol];
          ((float*)Cp)[(size_t)grow * ldc + gcol] = sigf(v);
        }
      }
    }
  }
}

// ---------------- fused LSTM scan + encoder + VQ + p1 ----------------
// one block (448 thr = 7 waves) per batch; thread r<400 owns gate rows {r, r+400}
// as 100 dwords of fp8x4 (x16 scale) = 100 VGPRs -> fits the allocator's
// 128-VGPR budget (2 blocks/CU) with NO spill, by construction.
__global__ __attribute__((amdgpu_flat_work_group_size(448, 448), amdgpu_waves_per_eu(4, 4)))
void lstm_enc(
    const u16* __restrict__ gates, const unsigned* __restrict__ Wq,
    const float* __restrict__ biasc,
    const float* __restrict__ Wenc, const float* __restrict__ b_enc,
    const float* __restrict__ emb, const float* __restrict__ W1,
    const float* __restrict__ b1, const float* __restrict__ noise,
    float* __restrict__ p1) {
  __shared__ __attribute__((aligned(16))) float sh_hf[HID];
  __shared__ float sh_g[G4H];
  __shared__ __attribute__((aligned(16))) float sh_ze[LATENT];
  __shared__ float sh_zq[LATENT];
  __shared__ float sh_rd[448];
  __shared__ int sh_ri[448];
  const int r = threadIdx.x;
  const int b = blockIdx.x;
  const bool active = (r < 400);

  unsigned wv[100];
  float biasA = 0.f, biasB = 0.f;
  if (active) {
#pragma unroll
    for (int j = 0; j < 100; ++j) wv[j] = Wq[(size_t)j * 400 + r];
    biasA = biasc[r];
    biasB = biasc[r + 400];
  }
  if (r < HID) sh_hf[r] = 0.f;
  float c = 0.f;
  float gvA = 0.f, gvB = 0.f;
  if (active) {
    gvA = b2f(gates[(size_t)(b * TLEN) * LDG + r]);
    gvB = b2f(gates[(size_t)(b * TLEN) * LDG + r + 400]);
  }
  __syncthreads();

  for (int t = 0; t < TLEN; ++t) {
    float gvA_n = 0.f, gvB_n = 0.f;
    if (active && t + 1 < TLEN) {
      gvA_n = b2f(gates[(size_t)(b * TLEN + t + 1) * LDG + r]);
      gvB_n = b2f(gates[(size_t)(b * TLEN + t + 1) * LDG + r + 400]);
    }

    if (active) {
      float sA = 0.f, sB = 0.f;
      const float4* H = (const float4*)sh_hf;
#pragma unroll
      for (int q = 0; q < 50; ++q) {
        float4 h4 = H[q];  // h[4q .. 4q+3]
        unsigned w0 = wv[2 * q], w1 = wv[2 * q + 1];
        f32x2 lo0 = __builtin_amdgcn_cvt_pk_f32_fp8(w0, 0);  // (A_k, B_k)
        f32x2 hi0 = __builtin_amdgcn_cvt_pk_f32_fp8(w0, 1);  // (A_k1, B_k1)
        sA = fmaf(lo0.x, h4.x, sA); sB = fmaf(lo0.y, h4.x, sB);
        sA = fmaf(hi0.x, h4.y, sA); sB = fmaf(hi0.y, h4.y, sB);
        f32x2 lo1 = __builtin_amdgcn_cvt_pk_f32_fp8(w1, 0);
        f32x2 hi1 = __builtin_amdgcn_cvt_pk_f32_fp8(w1, 1);
        sA = fmaf(lo1.x, h4.z, sA); sB = fmaf(lo1.y, h4.z, sB);
        sA = fmaf(hi1.x, h4.w, sA); sB = fmaf(hi1.y, h4.w, sB);
      }
      sh_g[r] = biasA + gvA + sA * 0.0625f;
      sh_g[r + 400] = biasB + gvB + sB * 0.0625f;
    }
    __syncthreads();  // gates visible; all sh_hf reads complete
    if (r < HID) {
      float gi = sh_g[r], gf = sh_g[HID + r], gg = sh_g[2 * HID + r], go = sh_g[3 * HID + r];
      c = sigf(gf) * c + sigf(gi) * tanh_fast(gg);
      sh_hf[r] = sigf(go) * tanh_fast(c);
    }
    __syncthreads();  // new h visible
    gvA = gvA_n; gvB = gvB_n;
  }

  // encoder: z_e = h @ Wenc^T + b_enc
  if (r < LATENT) {
    float z = b_enc[r];
#pragma unroll 4
    for (int k = 0; k < HID; ++k) z = fmaf(Wenc[(size_t)r * HID + k], sh_hf[k], z);
    sh_ze[r] = z;
  }
  __syncthreads();

  // VQ: argmin_k ||e_k||^2 - 2 z_e . e_k
  float best = INFINITY; int bi = 0;
  for (int k = r; k < NCODES; k += 448) {
    float d = 0.f;
#pragma unroll
    for (int q = 0; q < LATENT / 4; ++q) {
      float4 e = *(const float4*)&emb[(size_t)k * LATENT + q * 4];
      float4 z = *(const float4*)&sh_ze[q * 4];
      d += e.x * (e.x - 2.f * z.x) + e.y * (e.y - 2.f * z.y)
         + e.z * (e.z - 2.f * z.z) + e.w * (e.w - 2.f * z.w);
    }
    if (d < best) { best = d; bi = k; }
  }
  sh_rd[r] = best; sh_ri[r] = bi;
  __syncthreads();
  for (int s = 256; s > 0; s >>= 1) {
    if (r < s && r + s < 448) {
      float od = sh_rd[r + s]; int oi = sh_ri[r + s];
      if (od < sh_rd[r] || (od == sh_rd[r] && oi < sh_ri[r])) { sh_rd[r] = od; sh_ri[r] = oi; }
    }
    __syncthreads();
  }
  const int kmin = sh_ri[0];
  if (r < LATENT) sh_zq[r] = emb[(size_t)kmin * LATENT + r];
  __syncthreads();

  // p1[b][j] = b1 + W1[:,0:128].zq + W1[:,1664:2432].noise  (pad cols 200..255 = 0)
  if (r < 256) {
    float v = 0.f;
    if (r < HID) {
      v = b1[r];
      const float* wrow = W1 + (size_t)r * 2432;
#pragma unroll 4
      for (int d = 0; d < LATENT; ++d) v = fmaf(wrow[d], sh_zq[d], v);
      const float* nz = noise + (size_t)b * DIN;
#pragma unroll 4
      for (int d = 0; d < DIN; ++d) v = fmaf(wrow[1664 + d], nz[d], v);
    }
    p1[b * 256 + r] = v;
  }
}

// ---------------- host ----------------
extern "C" void kernel_launch(void* const* d_in, const int* in_sizes, int n_in,
                              void* d_out, int out_size, void* d_ws, size_t ws_size,
                              hipStream_t stream) {
  const float* x     = (const float*)d_in[0];
  const float* cond  = (const float*)d_in[1];
  const float* noise = (const float*)d_in[2];
  const float* W_ih  = (const float*)d_in[3];
  const float* W_hh  = (const float*)d_in[4];
  const float* b_ih  = (const float*)d_in[5];
  const float* b_hh  = (const float*)d_in[6];
  const float* W_enc = (const float*)d_in[7];
  const float* b_enc = (const float*)d_in[8];
  const float* emb   = (const float*)d_in[9];
  const float* W1    = (const float*)d_in[10];
  const float* b1    = (const float*)d_in[11];
  const float* W2    = (const float*)d_in[12];
  const float* b2    = (const float*)d_in[13];
  const float* W3    = (const float*)d_in[14];
  const float* b3    = (const float*)d_in[15];

  char* ws = (char*)d_ws;
  size_t off = 0;
  auto alloc = [&](size_t bytes) -> void* {
    void* p = ws + off; off += (bytes + 255) & ~(size_t)255; return p;
  };
  u16*      W_ihb = (u16*)alloc((size_t)896 * 768 * 2);
  u16*      W1cb  = (u16*)alloc((size_t)256 * 1536 * 2);
  u16*      W2b   = (u16*)alloc((size_t)512 * 256 * 2);
  u16*      W3b   = (u16*)alloc((size_t)768 * 512 * 2);
  float*    b2p   = (float*)alloc(512 * 4);
  unsigned* Wq    = (unsigned*)alloc((size_t)100 * 400 * 4);
  float*    biasc = (float*)alloc(G4H * 4);
  u16*      gates = (u16*)alloc((size_t)MROWS * LDG * 2);
  float*    p1    = (float*)alloc(256 * 256 * 4);
  u16*      h1    = (u16*)alloc((size_t)MROWS * LDH1 * 2);
  u16*      h2    = (u16*)alloc((size_t)MROWS * LDH2 * 2);

  cvt_pad<<<dim3((896 * 768 + 255) / 256), 256, 0, stream>>>(W_ih, W_ihb, 800, 768, 768, 0, 896, 768);
  cvt_pad<<<dim3((256 * 1536 + 255) / 256), 256, 0, stream>>>(W1, W1cb, 200, 1536, 2432, 128, 256, 1536);
  cvt_pad<<<dim3((512 * 256 + 255) / 256), 256, 0, stream>>>(W2, W2b, 400, 200, 200, 0, 512, 256);
  cvt_pad<<<dim3((768 * 512 + 255) / 256), 256, 0, stream>>>(W3, W3b, 768, 400, 400, 0, 768, 512);
  pad_f32<<<dim3(2), 256, 0, stream>>>(b2, b2p, 400, 512);
  pack_whh_fp8<<<dim3((100 * 400 + 255) / 256), 256, 0, stream>>>(W_hh, Wq, b_ih, b_hh, biasc);

  // gates = x @ W_ih^T  (bias added in lstm kernel), bf16 out, ld 896
  gemm_bf16<true, EPI_GATES><<<dim3(LDG / 128, MROWS / 128), 256, 0, stream>>>(
      x, W_ihb, gates, 768, LDG, nullptr);

  // LSTM scan + encoder + VQ + p1
  lstm_enc<<<dim3(NB), 448, 0, stream>>>(gates, Wq, biasc, W_enc, b_enc,
                                         emb, W1, b1, noise, p1);

  // h1 = relu(cond @ W1c^T + p1[b])
  gemm_bf16<true, EPI_H1><<<dim3(LDH1 / 128, MROWS / 128), 256, 0, stream>>>(
      cond, W1cb, h1, DCOND, LDH1, p1);
  // h2 = relu(h1 @ W2^T + b2)
  gemm_bf16<false, EPI_H2><<<dim3(LDH2 / 128, MROWS / 128), 256, 0, stream>>>(
      h1, W2b, h2, LDH1, LDH2, b2p);
  // out = sigmoid(h2 @ W3^T + b3)
  gemm_bf16<false, EPI_OUT><<<dim3(NOUT / 128, MROWS / 128), 256, 0, stream>>>(
      h2, W3b, (float*)d_out, LDH2, NOUT, b3);
}

// Round 6
// 644.154 us; speedup vs baseline: 1.5917x; 1.5917x over previous
//
#include <hip/hip_runtime.h>
#include <math.h>

typedef unsigned short u16;
typedef u16 u16x8 __attribute__((ext_vector_type(8)));
typedef __bf16 bf16x8 __attribute__((ext_vector_type(8)));
typedef float f32x4 __attribute__((ext_vector_type(4)));
typedef float f32x2 __attribute__((ext_vector_type(2)));

#define HID 200
#define G4H 800
#define TLEN 128
#define LATENT 128
#define NCODES 1024
#define DIN 768
#define DCOND 1536
#define NB 256
#define MROWS (NB * TLEN)
#define LDG 896
#define LDH1 256
#define LDH2 512
#define NOUT 768

__device__ __forceinline__ u16 f2b(float f) {
  union { float f; unsigned u; } v; v.f = f;
  unsigned r = v.u + 0x7fffu + ((v.u >> 16) & 1u);
  return (u16)(r >> 16);
}
__device__ __forceinline__ float b2f(u16 h) {
  union { unsigned u; float f; } v; v.u = ((unsigned)h) << 16;
  return v.f;
}
__device__ __forceinline__ float sigf(float x) { return 1.f / (1.f + __expf(-x)); }
__device__ __forceinline__ float tanh_fast(float x) {
  return 1.f - 2.f / (__expf(2.f * x) + 1.f);
}

// manual fp8 e4m3fn encode (OCP; matches gfx950 v_cvt_pk_f32_fp8 decode)
__device__ __forceinline__ unsigned enc_e4m3(float v) {
  union { float f; unsigned u; } x; x.f = v;
  unsigned s = (x.u >> 31) << 7;
  float a = fabsf(v);
  if (a == 0.f) return s;
  if (a >= 448.f) return s | 0x7E;
  int exp = (int)((x.u >> 23) & 0xFF) - 127;
  unsigned man = (x.u >> 20) & 0x7;
  unsigned rnd = (x.u >> 19) & 1;
  man += rnd;
  if (man > 7) { man = 0; exp += 1; }
  int be = exp + 7;
  if (be >= 16) return s | 0x7E;
  if (be <= 0) {
    int q = (int)(a * 512.f + 0.5f);
    if (q > 7) q = 7;
    return s | (unsigned)q;
  }
  return s | ((unsigned)be << 4) | man;
}

// async global->LDS, 16B per lane
__device__ __forceinline__ void gl16(const void* g, void* l) {
  __builtin_amdgcn_global_load_lds(
      (const __attribute__((address_space(1))) void*)g,
      (__attribute__((address_space(3))) void*)l, 16, 0, 0);
}

__device__ __forceinline__ unsigned cvtpk(float a, float b) {
  unsigned r;
  asm("v_cvt_pk_bf16_f32 %0, %1, %2" : "=v"(r) : "v"(a), "v"(b));
  return r;
}

// ---------------- weight convert + pad ----------------
__global__ void cvt_pad(const float* __restrict__ src, u16* __restrict__ dst,
                        int nr, int nc, int lds, int col0, int NRp, int KP) {
  int i = blockIdx.x * blockDim.x + threadIdx.x;
  if (i >= NRp * KP) return;
  int r = i / KP, c = i - r * KP;
  float v = (r < nr && c < nc) ? src[(size_t)r * lds + col0 + c] : 0.f;
  dst[i] = f2b(v);
}

__global__ void pad_f32(const float* __restrict__ src, float* __restrict__ dst,
                        int n, int npad) {
  int i = blockIdx.x * blockDim.x + threadIdx.x;
  if (i < npad) dst[i] = (i < n) ? src[i] : 0.f;
}

// W_hh [800][200] f32 -> Wq[kk*200+u] = fp8x4( 16*W[u][kk], 16*W[200+u][kk],
//                                              16*W[400+u][kk], 16*W[600+u][kk] )
// kk = 0..199 (= team*40 + j). Also biasc896[col] = b_ih+b_hh (0-padded to 896).
__global__ void pack_whh5(const float* __restrict__ Whh, unsigned* __restrict__ Wq,
                          const float* __restrict__ b_ih, const float* __restrict__ b_hh,
                          float* __restrict__ biasc) {
  int i = blockIdx.x * blockDim.x + threadIdx.x;
  if (i < 200 * 200) {
    int kk = i / 200, u = i - kk * 200;
    unsigned b0 = enc_e4m3(16.f * Whh[(size_t)u * HID + kk]);
    unsigned b1 = enc_e4m3(16.f * Whh[(size_t)(200 + u) * HID + kk]);
    unsigned b2 = enc_e4m3(16.f * Whh[(size_t)(400 + u) * HID + kk]);
    unsigned b3 = enc_e4m3(16.f * Whh[(size_t)(600 + u) * HID + kk]);
    Wq[i] = b0 | (b1 << 8) | (b2 << 16) | (b3 << 24);
  }
  if (i < LDG) biasc[i] = (i < G4H) ? (b_ih[i] + b_hh[i]) : 0.f;
}

// ---------------- bf16 MFMA GEMM: C[M,N] = A[M,K] * B[N,K]^T (+epilogue) ----------------
enum { EPI_GATES = 0, EPI_H1 = 1, EPI_H2 = 2, EPI_OUT = 3 };

__device__ __forceinline__ f32x4 mfma16(bf16x8 a, bf16x8 b, f32x4 c) {
  return __builtin_amdgcn_mfma_f32_16x16x32_bf16(a, b, c, 0, 0, 0);
}

template<bool AF32, int EPI>
__global__ __launch_bounds__(256) void gemm_bf16(
    const void* __restrict__ Ap, const u16* __restrict__ Bp,
    void* __restrict__ Cp, int K, int ldc, const float* __restrict__ bias) {
  __shared__ __attribute__((aligned(16))) char AsRaw[AF32 ? 128 * 32 * 4 : 128 * 32 * 2];
  __shared__ __attribute__((aligned(16))) u16 Bs[128 * 32];
  float* Asf = (float*)AsRaw;
  u16* As16 = (u16*)AsRaw;

  const int t = threadIdx.x;
  const int tileN = blockIdx.x * 128;
  const int tileM = blockIdx.y * 128;
  const int l = t & 63;
  const int w = t >> 6;
  const int wr = (w >> 1) * 64;
  const int wc = (w & 1) * 64;
  const int fr = l & 15;
  const int fg = l >> 4;

  const u16* bsrc[2];
  u16* bdst[2];
#pragma unroll
  for (int j = 0; j < 2; ++j) {
    int tb = w * 1024 + j * 4096 + (t & 63) * 16;
    int row = tb >> 6, gd = (tb >> 4) & 3;
    bsrc[j] = Bp + (size_t)(tileN + row) * K + ((gd ^ ((row >> 1) & 3)) << 3);
    bdst[j] = Bs + w * 512 + j * 2048;
  }
  const float* asrcF[4];
  float* adstF[4];
  const u16* asrcH[2];
  u16* adstH[2];
  if constexpr (AF32) {
#pragma unroll
    for (int j = 0; j < 4; ++j) {
      int tb = w * 1024 + j * 4096 + (t & 63) * 16;
      int row = tb >> 7, gd = (tb >> 4) & 7;
      asrcF[j] = (const float*)Ap + (size_t)(tileM + row) * K + ((gd ^ (row & 7)) << 2);
      adstF[j] = Asf + w * 256 + j * 1024;
    }
  } else {
#pragma unroll
    for (int j = 0; j < 2; ++j) {
      int tb = w * 1024 + j * 4096 + (t & 63) * 16;
      int row = tb >> 6, gd = (tb >> 4) & 3;
      asrcH[j] = (const u16*)Ap + (size_t)(tileM + row) * K + ((gd ^ ((row >> 1) & 3)) << 3);
      adstH[j] = As16 + w * 512 + j * 2048;
    }
  }

  f32x4 acc[4][4];
#pragma unroll
  for (int m = 0; m < 4; ++m)
#pragma unroll
    for (int n = 0; n < 4; ++n) {
      f32x4 z = {0.f, 0.f, 0.f, 0.f};
      acc[m][n] = z;
    }

  for (int k0 = 0; k0 < K; k0 += 32) {
#pragma unroll
    for (int j = 0; j < 2; ++j) { gl16(bsrc[j], bdst[j]); bsrc[j] += 32; }
    if constexpr (AF32) {
#pragma unroll
      for (int j = 0; j < 4; ++j) { gl16(asrcF[j], adstF[j]); asrcF[j] += 32; }
    } else {
#pragma unroll
      for (int j = 0; j < 2; ++j) { gl16(asrcH[j], adstH[j]); asrcH[j] += 32; }
    }
    __syncthreads();

    bf16x8 av[4], bv[4];
#pragma unroll
    for (int m = 0; m < 4; ++m) {
      const int row = wr + m * 16 + fr;
      if constexpr (AF32) {
        const int g0 = (2 * fg) ^ (row & 7);
        const int g1 = (2 * fg + 1) ^ (row & 7);
        float4 p0 = *(const float4*)(Asf + row * 32 + g0 * 4);
        float4 p1 = *(const float4*)(Asf + row * 32 + g1 * 4);
        uint4 u;
        u.x = cvtpk(p0.x, p0.y); u.y = cvtpk(p0.z, p0.w);
        u.z = cvtpk(p1.x, p1.y); u.w = cvtpk(p1.z, p1.w);
        av[m] = __builtin_bit_cast(bf16x8, u);
      } else {
        const int g = fg ^ ((row >> 1) & 3);
        av[m] = __builtin_bit_cast(bf16x8, *(const u16x8*)(As16 + row * 32 + g * 8));
      }
    }
#pragma unroll
    for (int n = 0; n < 4; ++n) {
      const int row = wc + n * 16 + fr;
      const int g = fg ^ ((row >> 1) & 3);
      bv[n] = __builtin_bit_cast(bf16x8, *(const u16x8*)(Bs + row * 32 + g * 8));
    }
#pragma unroll
    for (int m = 0; m < 4; ++m)
#pragma unroll
      for (int n = 0; n < 4; ++n)
        acc[m][n] = mfma16(av[m], bv[n], acc[m][n]);
    __syncthreads();
  }

#pragma unroll
  for (int m = 0; m < 4; ++m) {
#pragma unroll
    for (int n = 0; n < 4; ++n) {
      const int gcol = tileN + wc + n * 16 + fr;
      const int growb = tileM + wr + m * 16 + fg * 4;
#pragma unroll
      for (int r = 0; r < 4; ++r) {
        const int grow = growb + r;
        float v = acc[m][n][r];
        if constexpr (EPI == EPI_GATES) {
          v += bias[gcol];   // b_ih + b_hh folded here
          ((u16*)Cp)[(size_t)grow * ldc + gcol] = f2b(v);
        } else if constexpr (EPI == EPI_H1) {
          v += bias[(grow >> 7) * 256 + gcol];
          v = fmaxf(v, 0.f);
          ((u16*)Cp)[(size_t)grow * ldc + gcol] = f2b(v);
        } else if constexpr (EPI == EPI_H2) {
          v += bias[gcol];
          v = fmaxf(v, 0.f);
          ((u16*)Cp)[(size_t)grow * ldc + gcol] = f2b(v);
        } else {
          v += bias[gcol];
          ((float*)Cp)[(size_t)grow * ldc + gcol] = sigf(v);
        }
      }
    }
  }
}

// ---------------- fused LSTM scan + encoder + VQ + p1 ----------------
// 1024 threads = 16 waves per block, one block per batch element.
// 5 teams x 200 lanes: thread (team,u) owns all 4 gate rows of unit u over a
// 40-wide k-slice as 40 fp8x4 dwords (x16 scale) -> fits even a 64-VGPR budget.
// Teams 1-4 write partials to LDS; team 0 combines + gate nonlinearity.
__global__ __attribute__((amdgpu_flat_work_group_size(1024, 1024), amdgpu_waves_per_eu(4, 4)))
void lstm_enc(
    const u16* __restrict__ gates, const unsigned* __restrict__ Wq,
    const float* __restrict__ Wenc, const float* __restrict__ b_enc,
    const float* __restrict__ emb, const float* __restrict__ W1,
    const float* __restrict__ b1, const float* __restrict__ noise,
    float* __restrict__ p1) {
  __shared__ __attribute__((aligned(16))) float sh_hf[HID];
  __shared__ __attribute__((aligned(16))) float sh_p[4][200][4];  // [gate][u][team-1]
  __shared__ __attribute__((aligned(16))) float sh_ze[LATENT];
  __shared__ float sh_zq[LATENT];
  __shared__ float sh_rd[1024];
  __shared__ int sh_ri[1024];
  const int t = threadIdx.x;
  const int b = blockIdx.x;
  const int team = t / 200;          // 0..4 (t<1000), 5 for idle tail
  const int u = t - team * 200;
  const bool act = (t < 1000);
  const bool lead = (t < 200);       // team 0

  unsigned wv[40];
  if (act) {
    const unsigned* wp = Wq + (size_t)(team * 40) * 200 + u;
#pragma unroll
    for (int j = 0; j < 40; ++j) wv[j] = wp[j * 200];
  }
  if (lead) sh_hf[u] = 0.f;
  float c = 0.f;
  float gv0 = 0.f, gv1 = 0.f, gv2 = 0.f, gv3 = 0.f;
  if (lead) {
    const u16* gr = gates + (size_t)(b * TLEN) * LDG;
    gv0 = b2f(gr[u]); gv1 = b2f(gr[200 + u]);
    gv2 = b2f(gr[400 + u]); gv3 = b2f(gr[600 + u]);
  }
  __syncthreads();

  for (int ts = 0; ts < TLEN; ++ts) {
    // prefetch next step's gate pre-activations (team 0 only)
    float gn0 = 0.f, gn1 = 0.f, gn2 = 0.f, gn3 = 0.f;
    if (lead && ts + 1 < TLEN) {
      const u16* gr = gates + (size_t)(b * TLEN + ts + 1) * LDG;
      gn0 = b2f(gr[u]); gn1 = b2f(gr[200 + u]);
      gn2 = b2f(gr[400 + u]); gn3 = b2f(gr[600 + u]);
    }

    float si = 0.f, sf = 0.f, sg = 0.f, so = 0.f;
    if (act) {
      const float* hbase = sh_hf + team * 40;
#pragma unroll
      for (int jq = 0; jq < 10; ++jq) {
        float4 h4 = *(const float4*)(hbase + jq * 4);
#pragma unroll
        for (int e = 0; e < 4; ++e) {
          unsigned wd = wv[jq * 4 + e];
          f32x2 lo = __builtin_amdgcn_cvt_pk_f32_fp8(wd, 0);  // (w_i, w_f)
          f32x2 hi = __builtin_amdgcn_cvt_pk_f32_fp8(wd, 1);  // (w_g, w_o)
          float h = (e == 0) ? h4.x : (e == 1) ? h4.y : (e == 2) ? h4.z : h4.w;
          si = fmaf(lo.x, h, si);
          sf = fmaf(lo.y, h, sf);
          sg = fmaf(hi.x, h, sg);
          so = fmaf(hi.y, h, so);
        }
      }
      if (team > 0) {
        sh_p[0][u][team - 1] = si;
        sh_p[1][u][team - 1] = sf;
        sh_p[2][u][team - 1] = sg;
        sh_p[3][u][team - 1] = so;
      }
    }
    __syncthreads();   // partials visible; all sh_hf reads complete
    if (lead) {
      float4 pi = *(const float4*)&sh_p[0][u][0];
      float4 pf = *(const float4*)&sh_p[1][u][0];
      float4 pg = *(const float4*)&sh_p[2][u][0];
      float4 po = *(const float4*)&sh_p[3][u][0];
      float gi = gv0 + (si + pi.x + pi.y + pi.z + pi.w) * 0.0625f;
      float gf = gv1 + (sf + pf.x + pf.y + pf.z + pf.w) * 0.0625f;
      float gg = gv2 + (sg + pg.x + pg.y + pg.z + pg.w) * 0.0625f;
      float go = gv3 + (so + po.x + po.y + po.z + po.w) * 0.0625f;
      c = sigf(gf) * c + sigf(gi) * tanh_fast(gg);
      sh_hf[u] = sigf(go) * tanh_fast(c);
    }
    __syncthreads();   // new h visible
    gv0 = gn0; gv1 = gn1; gv2 = gn2; gv3 = gn3;
  }

  // encoder: z_e = h @ Wenc^T + b_enc
  if (t < LATENT) {
    float z = b_enc[t];
#pragma unroll 4
    for (int k = 0; k < HID; ++k) z = fmaf(Wenc[(size_t)t * HID + k], sh_hf[k], z);
    sh_ze[t] = z;
  }
  __syncthreads();

  // VQ: argmin_k ||e_k||^2 - 2 z_e . e_k   (1024 threads = 1 code each)
  {
    float d = 0.f;
#pragma unroll
    for (int q = 0; q < LATENT / 4; ++q) {
      float4 e = *(const float4*)&emb[(size_t)t * LATENT + q * 4];
      float4 z = *(const float4*)&sh_ze[q * 4];
      d += e.x * (e.x - 2.f * z.x) + e.y * (e.y - 2.f * z.y)
         + e.z * (e.z - 2.f * z.z) + e.w * (e.w - 2.f * z.w);
    }
    sh_rd[t] = d; sh_ri[t] = t;
  }
  __syncthreads();
  for (int s = 512; s > 0; s >>= 1) {
    if (t < s) {
      float od = sh_rd[t + s]; int oi = sh_ri[t + s];
      if (od < sh_rd[t] || (od == sh_rd[t] && oi < sh_ri[t])) { sh_rd[t] = od; sh_ri[t] = oi; }
    }
    __syncthreads();
  }
  const int kmin = sh_ri[0];
  if (t < LATENT) sh_zq[t] = emb[(size_t)kmin * LATENT + t];
  __syncthreads();

  // p1[b][j] = b1 + W1[:,0:128].zq + W1[:,1664:2432].noise  (pad cols 200..255 = 0)
  if (t < 256) {
    float v = 0.f;
    if (t < HID) {
      v = b1[t];
      const float* wrow = W1 + (size_t)t * 2432;
#pragma unroll 4
      for (int d = 0; d < LATENT; ++d) v = fmaf(wrow[d], sh_zq[d], v);
      const float* nz = noise + (size_t)b * DIN;
#pragma unroll 4
      for (int d = 0; d < DIN; ++d) v = fmaf(wrow[1664 + d], nz[d], v);
    }
    p1[b * 256 + t] = v;
  }
}

// ---------------- host ----------------
extern "C" void kernel_launch(void* const* d_in, const int* in_sizes, int n_in,
                              void* d_out, int out_size, void* d_ws, size_t ws_size,
                              hipStream_t stream) {
  const float* x     = (const float*)d_in[0];
  const float* cond  = (const float*)d_in[1];
  const float* noise = (const float*)d_in[2];
  const float* W_ih  = (const float*)d_in[3];
  const float* W_hh  = (const float*)d_in[4];
  const float* b_ih  = (const float*)d_in[5];
  const float* b_hh  = (const float*)d_in[6];
  const float* W_enc = (const float*)d_in[7];
  const float* b_enc = (const float*)d_in[8];
  const float* emb   = (const float*)d_in[9];
  const float* W1    = (const float*)d_in[10];
  const float* b1    = (const float*)d_in[11];
  const float* W2    = (const float*)d_in[12];
  const float* b2    = (const float*)d_in[13];
  const float* W3    = (const float*)d_in[14];
  const float* b3    = (const float*)d_in[15];

  char* ws = (char*)d_ws;
  size_t off = 0;
  auto alloc = [&](size_t bytes) -> void* {
    void* p = ws + off; off += (bytes + 255) & ~(size_t)255; return p;
  };
  u16*      W_ihb = (u16*)alloc((size_t)896 * 768 * 2);
  u16*      W1cb  = (u16*)alloc((size_t)256 * 1536 * 2);
  u16*      W2b   = (u16*)alloc((size_t)512 * 256 * 2);
  u16*      W3b   = (u16*)alloc((size_t)768 * 512 * 2);
  float*    b2p   = (float*)alloc(512 * 4);
  unsigned* Wq    = (unsigned*)alloc((size_t)200 * 200 * 4);
  float*    biasc = (float*)alloc(LDG * 4);
  u16*      gates = (u16*)alloc((size_t)MROWS * LDG * 2);
  float*    p1    = (float*)alloc(256 * 256 * 4);
  u16*      h1    = (u16*)alloc((size_t)MROWS * LDH1 * 2);
  u16*      h2    = (u16*)alloc((size_t)MROWS * LDH2 * 2);

  cvt_pad<<<dim3((896 * 768 + 255) / 256), 256, 0, stream>>>(W_ih, W_ihb, 800, 768, 768, 0, 896, 768);
  cvt_pad<<<dim3((256 * 1536 + 255) / 256), 256, 0, stream>>>(W1, W1cb, 200, 1536, 2432, 128, 256, 1536);
  cvt_pad<<<dim3((512 * 256 + 255) / 256), 256, 0, stream>>>(W2, W2b, 400, 200, 200, 0, 512, 256);
  cvt_pad<<<dim3((768 * 512 + 255) / 256), 256, 0, stream>>>(W3, W3b, 768, 400, 400, 0, 768, 512);
  pad_f32<<<dim3(2), 256, 0, stream>>>(b2, b2p, 400, 512);
  pack_whh5<<<dim3((200 * 200 + 255) / 256), 256, 0, stream>>>(W_hh, Wq, b_ih, b_hh, biasc);

  // gates = x @ W_ih^T + (b_ih + b_hh), bf16 out, ld 896
  gemm_bf16<true, EPI_GATES><<<dim3(LDG / 128, MROWS / 128), 256, 0, stream>>>(
      x, W_ihb, gates, 768, LDG, biasc);

  // LSTM scan + encoder + VQ + p1
  lstm_enc<<<dim3(NB), 1024, 0, stream>>>(gates, Wq, W_enc, b_enc,
                                          emb, W1, b1, noise, p1);

  // h1 = relu(cond @ W1c^T + p1[b])
  gemm_bf16<true, EPI_H1><<<dim3(LDH1 / 128, MROWS / 128), 256, 0, stream>>>(
      cond, W1cb, h1, DCOND, LDH1, p1);
  // h2 = relu(h1 @ W2^T + b2)
  gemm_bf16<false, EPI_H2><<<dim3(LDH2 / 128, MROWS / 128), 256, 0, stream>>>(
      h1, W2b, h2, LDH1, LDH2, b2p);
  // out = sigmoid(h2 @ W3^T + b3)
  gemm_bf16<false, EPI_OUT><<<dim3(NOUT / 128, MROWS / 128), 256, 0, stream>>>(
      h2, W3b, (float*)d_out, LDH2, NOUT, b3);
}